// Round 13
// baseline (149.177 us; speedup 1.0000x reference)
//
#include <hip/hip_runtime.h>
#include <hip/hip_fp16.h>

static constexpr int Hh = 384;
static constexpr int Ww = 1280;
static constexpr int HW = Hh * Ww;            // 491520
static constexpr int NPIX = 2 * HW;
static constexpr int TILE_I = 24;             // output tile rows
static constexpr int TILE_J = 40;             // output tile cols
static constexpr int S_STEPS = 8;             // steps per launch; 24 = 3 x 8
static constexpr int RI = TILE_I + 2 * S_STEPS;   // 40
static constexpr int RJ = TILE_J + 2 * S_STEPS;   // 56
static constexpr int RR = RI * RJ;            // 2240
static constexpr int II = RI - 2;             // 38 interior rows
static constexpr int IJ = RJ - 2;             // 54 interior cols
static constexpr int NPAIR_ROW = IJ / 2;      // 27 pairs/row (exact)
static constexpr int NPAIR = II * NPAIR_ROW;  // 1026 pairs
static constexpr int BLOCK = 512;
static constexpr int PPQ = (RR + BLOCK - 1) / BLOCK;      // 5 region px / thread
static constexpr int PPR = (NPAIR + BLOCK - 1) / BLOCK;   // 3 pairs / thread
static constexpr int TI_T = Hh / TILE_I;      // 16
static constexpr int TJ_T = Ww / TILE_J;      // 32
static constexpr int GRID = 2 * TI_T * TJ_T;  // 1024 = exactly 4 blocks/CU
static constexpr int NXCD = 8;
static constexpr int CHUNK = GRID / NXCD;     // 128 (1024 % 8 == 0 -> bijective)
static constexpr float EPSF = 1e-9f;

// k order matches reference PADS: (di,dj) =
// k:   0       1       2       3       4       5       6       7
//    (+1,+1) (+1,0) (+1,-1) (0,+1) (0,-1) (-1,+1) (-1,0) (-1,-1)
static constexpr int DI[8] = { 1, 1, 1, 0, 0, -1, -1, -1 };
static constexpr int DJ[8] = { 1, 0, -1, 1, -1, 1, 0, -1 };

static __device__ __forceinline__ int iclamp(int v, int lo, int hi) {
    return min(max(v, lo), hi);
}

// Round-13: 3 launches x 8 steps, tile 24x40, FULL occupancy (32 waves/CU).
//
// Why (r12 counters): VALUBusy 28%, LDS ~35%, HBM 7%, occupancy ~20% --
// nothing saturated => the step loop is LATENCY-bound. At 2 blocks/CU
// (16 waves) the ~120cy LDS chains in 12 serial barrier phases can't be
// hidden. r12 (2x12, bigger region/phase) also showed the px-step RATE
// degrades as regions grow with fixed waves. So: shrink the tile until
// 4 blocks/CU co-reside -> 32 waves/CU (hardware max):
//   grid 1024 = 4/CU exact; LDS 17.9KB x 4 = 71.7KB <= 160KB;
//   32 waves/CU -> 64-VGPR budget, so per-thread state must fit ~64:
//   PPR=3, fp16-packed weights (r8-proven, absmax 1.0 << 3.48):
//   wp 12 + Cc 6 + pr 3 = 21 persistent + ~30 temps < 64 -> no spill.
//   __launch_bounds__(512,4): by the r3-r6 knob ledger (2nd arg = max
//   blocks/CU, CUDA semantics) this targets 4x8=32 waves -> 64 VGPRs.
// Redundancy 1.54x -> 12.1M px-steps/launch (r11: 10.7M, r12: 19.8M).
//
//  - Pairs start at odd region col -> all +-RJ+-1 tap bases even -> 8B
//    aligned (RJ=56 even preserves parity across rows).
//  - Shrinking active set, pair-granular (r8/r11/r12-verified): compute
//    pair if max(ring0,ring1) >= s; partner px below cutoff computes
//    bounded stale values never read by in-cutoff px later. Final step
//    does exact per-px center checks (maxring >= 8 -> ri in [8,32) = 24
//    tile rows; cols gated per px to [8,48) = 40 tile cols).
//  - Out-of-image region px hold clamped duplicates; never reach the
//    center (image-boundary px have weight 0 toward OOB neighbors, from
//    the reference's zero-padded guidance).
//  - blur/din NOT __restrict__ (r11 aliasing fix); launch 1 uses
//    FIRST=true to stage d0 from blur directly.
template <bool FIRST>
__global__ __launch_bounds__(BLOCK, 4)
void mega(
    const float* __restrict__ g,
    const float* blur,
    const float* __restrict__ sparse,
    const float* din,
    float* __restrict__ dout)
{
    __shared__ float sd[2][RR];

    const int tid = threadIdx.x;
    // XCD-aware bijective swizzle (1024 = 8*128): neighbor tiles share
    // halo reads within one XCD's private L2.
    int bx = ((int)blockIdx.x % NXCD) * CHUNK + (int)blockIdx.x / NXCD;
    const int tj = bx % TJ_T; bx /= TJ_T;
    const int ti = bx % TI_T;
    const int b  = bx / TI_T;
    const int oi = ti * TILE_I - S_STEPS;  // region origin (image coords)
    const int oj = tj * TILE_J - S_STEPS;

    const float* blurb = blur + (size_t)b * HW;
    const float* dinb  = (FIRST ? blur : din) + (size_t)b * HW;
    const float* gb    = g + (size_t)b * 8 * HW;

    // --- stage d0 over the whole region (image-clamped) ---
#pragma unroll
    for (int q = 0; q < PPQ; q++) {
        int p = tid + q * BLOCK;
        if (p < RR) {
            int ri = p / RJ, rj = p - ri * RJ;
            int gi = iclamp(oi + ri, 0, Hh - 1);
            int gj = iclamp(oj + rj, 0, Ww - 1);
            sd[0][p] = dinb[gi * Ww + gj];
        }
    }

    // --- fp16 weights + fp32 C per PAIR; registers for all 8 steps.
    // wp[q][k] = half2( w_k[px0], w_k[px1] ); Cc[q] = (C0, C1);
    // pr[q] = region offset of px0 (low 16) | max(ring0,ring1) << 16 ---
    __half2 wp[PPR][8];
    float2  Cc[PPR];
    int     pr[PPR];
#pragma unroll
    for (int q = 0; q < PPR; q++) {
        int pi = tid + q * BLOCK;
        if (pi < NPAIR) {
            int r0 = pi / NPAIR_ROW;
            int c0 = pi - r0 * NPAIR_ROW;
            int ri = 1 + r0;
            int rj = 1 + 2 * c0;           // odd -> aligned b64 tap bases
            int p  = ri * RJ + rj;
            int rngr = min(ri, RI - 1 - ri);
            int rng0 = min(rngr, min(rj,     RJ - 1 - rj));
            int rng1 = min(rngr, min(rj + 1, RJ - 2 - rj));
            pr[q] = p | (max(rng0, rng1) << 16);
            float Cv[2], wv[2][8];
#pragma unroll
            for (int x = 0; x < 2; x++) {
                int gi = iclamp(oi + ri, 0, Hh - 1);
                int gj = iclamp(oj + rj + x, 0, Ww - 1);
                float v[8];
                float a = EPSF;
#pragma unroll
                for (int k = 0; k < 8; k++) {
                    int ii = gi + DI[k], jj = gj + DJ[k];
                    float gv = 0.0f;
                    if (ii >= 0 && ii < Hh && jj >= 0 && jj < Ww)
                        gv = gb[k * HW + ii * Ww + jj];
                    v[k] = gv;
                    a += fabsf(gv);
                }
                float inv = 1.0f / a, gs = 0.0f;
#pragma unroll
                for (int k = 0; k < 8; k++) { v[k] *= inv; gs += v[k]; }
                int idx = gi * Ww + gj;
                float rawv = blurb[idx];
                bool m = sparse[b * HW + idx] > 0.0f; // sparse>=0; sign==1 iff >0
                Cv[x] = m ? rawv : (1.0f - gs) * rawv;
#pragma unroll
                for (int k = 0; k < 8; k++) wv[x][k] = m ? 0.0f : v[k];
            }
            Cc[q] = make_float2(Cv[0], Cv[1]);
#pragma unroll
            for (int k = 0; k < 8; k++)
                wp[q][k] = __halves2half2(__float2half(wv[0][k]),
                                          __float2half(wv[1][k]));
        } else {
            pr[q] = 0;                      // ring 0 -> never active
            Cc[q] = make_float2(0.0f, 0.0f);
#pragma unroll
            for (int k = 0; k < 8; k++)
                wp[q][k] = __halves2half2(__float2half(0.0f), __float2half(0.0f));
        }
    }
    __syncthreads();

    // --- steps 1..7 in LDS; step s touches only pairs with maxring >= s ---
    int cur = 0;
#pragma unroll 1
    for (int s = 1; s < S_STEPS; ++s) {
        const float* s0 = sd[cur];
        float* s1 = sd[cur ^ 1];
#pragma unroll
        for (int q = 0; q < PPR; q++) {
            if ((pr[q] >> 16) >= s) {
                int p = pr[q] & 0xffff;
                // 12 distinct taps as 6 aligned b64 loads
                float2 uA = *(const float2*)(s0 + p - RJ - 1);   // (i-1: j-1, j)
                float2 uB = *(const float2*)(s0 + p - RJ + 1);   // (i-1: j+1, j+2)
                float2 mA = *(const float2*)(s0 + p - 1);        // (i  : j-1, j)
                float2 mB = *(const float2*)(s0 + p + 1);        // (i  : j+1, j+2)
                float2 dA = *(const float2*)(s0 + p + RJ - 1);   // (i+1: j-1, j)
                float2 dB = *(const float2*)(s0 + p + RJ + 1);   // (i+1: j+1, j+2)
                float ax = Cc[q].x, ay = Cc[q].y;
                ax = fmaf(__low2float (wp[q][0]), dB.x, ax);
                ay = fmaf(__high2float(wp[q][0]), dB.y, ay);
                ax = fmaf(__low2float (wp[q][1]), dA.y, ax);
                ay = fmaf(__high2float(wp[q][1]), dB.x, ay);
                ax = fmaf(__low2float (wp[q][2]), dA.x, ax);
                ay = fmaf(__high2float(wp[q][2]), dA.y, ay);
                ax = fmaf(__low2float (wp[q][3]), mB.x, ax);
                ay = fmaf(__high2float(wp[q][3]), mB.y, ay);
                ax = fmaf(__low2float (wp[q][4]), mA.x, ax);
                ay = fmaf(__high2float(wp[q][4]), mA.y, ay);
                ax = fmaf(__low2float (wp[q][5]), uB.x, ax);
                ay = fmaf(__high2float(wp[q][5]), uB.y, ay);
                ax = fmaf(__low2float (wp[q][6]), uA.y, ax);
                ay = fmaf(__high2float(wp[q][6]), uB.x, ay);
                ax = fmaf(__low2float (wp[q][7]), uA.x, ax);
                ay = fmaf(__high2float(wp[q][7]), uA.y, ay);
                s1[p]     = ax;
                s1[p + 1] = ay;
            }
        }
        __syncthreads();
        cur ^= 1;
    }

    // --- step 8: per-px center checks, write straight to global ---
    const float* s0 = sd[cur];
#pragma unroll
    for (int q = 0; q < PPR; q++) {
        if ((pr[q] >> 16) >= S_STEPS) {
            int p = pr[q] & 0xffff;
            float2 uA = *(const float2*)(s0 + p - RJ - 1);
            float2 uB = *(const float2*)(s0 + p - RJ + 1);
            float2 mA = *(const float2*)(s0 + p - 1);
            float2 mB = *(const float2*)(s0 + p + 1);
            float2 dA = *(const float2*)(s0 + p + RJ - 1);
            float2 dB = *(const float2*)(s0 + p + RJ + 1);
            float ax = Cc[q].x, ay = Cc[q].y;
            ax = fmaf(__low2float (wp[q][0]), dB.x, ax);
            ay = fmaf(__high2float(wp[q][0]), dB.y, ay);
            ax = fmaf(__low2float (wp[q][1]), dA.y, ax);
            ay = fmaf(__high2float(wp[q][1]), dB.x, ay);
            ax = fmaf(__low2float (wp[q][2]), dA.x, ax);
            ay = fmaf(__high2float(wp[q][2]), dA.y, ay);
            ax = fmaf(__low2float (wp[q][3]), mB.x, ax);
            ay = fmaf(__high2float(wp[q][3]), mB.y, ay);
            ax = fmaf(__low2float (wp[q][4]), mA.x, ax);
            ay = fmaf(__high2float(wp[q][4]), mA.y, ay);
            ax = fmaf(__low2float (wp[q][5]), uB.x, ax);
            ay = fmaf(__high2float(wp[q][5]), uB.y, ay);
            ax = fmaf(__low2float (wp[q][6]), uA.y, ax);
            ay = fmaf(__high2float(wp[q][6]), uB.x, ay);
            ax = fmaf(__low2float (wp[q][7]), uA.x, ax);
            ay = fmaf(__high2float(wp[q][7]), uA.y, ay);
            int ri = p / RJ, rj = p - ri * RJ;
            // maxring >= 8 guarantees ri in [8, RI-8); cols per px.
            int gbase = b * HW + (oi + ri) * Ww + (oj + rj);
            if (rj >= S_STEPS && rj < RJ - S_STEPS)
                dout[gbase]     = ax;
            if (rj + 1 >= S_STEPS && rj + 1 < RJ - S_STEPS)
                dout[gbase + 1] = ay;
        }
    }
}

extern "C" void kernel_launch(void* const* d_in, const int* in_sizes, int n_in,
                              void* d_out, int out_size, void* d_ws, size_t ws_size,
                              hipStream_t stream) {
    const float* guidance = (const float*)d_in[0];
    const float* blur     = (const float*)d_in[1];
    const float* sparse   = (const float*)d_in[2];
    float* out = (float*)d_out;

    char* ws = (char*)d_ws;
    float* bufA = (float*)ws;
    float* bufB = bufA + NPIX;

    // 24 steps = 3 launches x 8 fused steps
    mega<true ><<<GRID, BLOCK, 0, stream>>>(guidance, blur, sparse, nullptr, bufA);
    mega<false><<<GRID, BLOCK, 0, stream>>>(guidance, blur, sparse, bufA, bufB);
    mega<false><<<GRID, BLOCK, 0, stream>>>(guidance, blur, sparse, bufB, out);
}

// Round 14
// 129.028 us; speedup vs baseline: 1.1562x; 1.1562x over previous
//
#include <hip/hip_runtime.h>
#include <hip/hip_fp16.h>

static constexpr int Hh = 384;
static constexpr int Ww = 1280;
static constexpr int HW = Hh * Ww;            // 491520
static constexpr int NPIX = 2 * HW;
static constexpr int TILE_I = 48;             // output tile rows
static constexpr int TILE_J = 40;             // output tile cols
static constexpr int S_STEPS = 8;             // steps per launch; 24 = 3 x 8
static constexpr int RI = TILE_I + 2 * S_STEPS;   // 64
static constexpr int RJ = TILE_J + 2 * S_STEPS;   // 56
static constexpr int RR = RI * RJ;            // 3584
static constexpr int II = RI - 2;             // 62 interior rows
static constexpr int IJ = RJ - 2;             // 54 interior cols
static constexpr int NPAIR_ROW = IJ / 2;      // 27 pairs/row (exact)
static constexpr int NPAIR = II * NPAIR_ROW;  // 1674 pairs
static constexpr int BLOCK = 512;
static constexpr int PPQ = RR / BLOCK;        // 7 region px / thread (exact)
static constexpr int PPR = (NPAIR + BLOCK - 1) / BLOCK;   // 4 pairs / thread
static constexpr int TI_T = Hh / TILE_I;      // 8
static constexpr int TJ_T = Ww / TILE_J;      // 32
static constexpr int GRID = 2 * TI_T * TJ_T;  // 512 = exactly 2 blocks/CU
static constexpr int NXCD = 8;
static constexpr int CHUNK = GRID / NXCD;     // 64 (512 % 8 == 0 -> bijective)
static constexpr float EPSF = 1e-9f;

// k order matches reference PADS: (di,dj) =
// k:   0       1       2       3       4       5       6       7
//    (+1,+1) (+1,0) (+1,-1) (0,+1) (0,-1) (-1,+1) (-1,0) (-1,-1)
__device__ __constant__ int DI_c[8] = { 1, 1, 1, 0, 0, -1, -1, -1 };
__device__ __constant__ int DJ_c[8] = { 1, 0, -1, 1, -1, 1, 0, -1 };

static __device__ __forceinline__ int iclamp(int v, int lo, int hi) {
    return min(max(v, lo), hi);
}

// Round-14: r11's engine (3x8, tile 48x40, fp32 pair weights, 2 blocks/CU
// -- the measured best at 140.0us; r12 2x12 and r13 full-occupancy both
// regressed) with ONE change: weights/C precomputed ONCE by affinity_norm
// (the round-0 harness-proven kernel) instead of recomputed from guidance
// in every launch. r11's per-launch setup (~11us: 16 scattered guidance
// loads + ~170 VALU per thread) becomes two coalesced float4 loads + cvt.

// Precompute per pixel: w'_k (fp16, zeroed where sparse-clamped) and
// C = m ? raw : (1-gate_sum)*raw. Each step is then d' = C + sum w'_k d_k.
__global__ void affinity_norm(const float* __restrict__ g,
                              const float* __restrict__ raw,
                              const float* __restrict__ sparse,
                              __half* __restrict__ wbuf,
                              float* __restrict__ cbuf) {
    int idx = blockIdx.x * blockDim.x + threadIdx.x;
    if (idx >= NPIX) return;
    int b = idx / HW;
    int r = idx - b * HW;
    int i = r / Ww;
    int j = r - i * Ww;

    const float* gb = g + (size_t)b * 8 * HW;
    float v[8];
    float a = EPSF;
#pragma unroll
    for (int k = 0; k < 8; k++) {
        int ii = i + DI_c[k], jj = j + DJ_c[k];
        float gv = 0.0f;
        if (ii >= 0 && ii < Hh && jj >= 0 && jj < Ww)
            gv = gb[k * HW + ii * Ww + jj];
        v[k] = gv;
        a += fabsf(gv);
    }
    float inv = 1.0f / a, gs = 0.0f;
#pragma unroll
    for (int k = 0; k < 8; k++) { v[k] *= inv; gs += v[k]; }

    float rawv = raw[idx];
    bool m = sparse[idx] > 0.0f;   // sparse >= 0 always; sign(s)==1 iff s>0
    cbuf[idx] = m ? rawv : (1.0f - gs) * rawv;
    __half wv[8];
#pragma unroll
    for (int k = 0; k < 8; k++) wv[k] = __float2half(m ? 0.0f : v[k]);
    *(float4*)(wbuf + (size_t)idx * 8) = *(const float4*)wv;
}

// 8 fused Jacobi steps; pair inner loop (r8/r11-verified).
//  - Pairs start at odd region col -> all +-RJ+-1 tap bases even -> 8B
//    aligned (RJ=56 even preserves parity across rows).
//  - Shrinking active set, pair-granular: compute pair if
//    max(ring0,ring1) >= s; partner px below cutoff computes bounded
//    stale values never read by in-cutoff px later. Final step does
//    exact per-px center checks.
//  - Out-of-image region px hold clamped duplicates; never reach the
//    center (image-boundary px have weight 0 toward OOB neighbors).
//  - blur/din NOT __restrict__ (r11 aliasing fix); launch 1 uses
//    FIRST=true to stage d0 from blur directly.
//  - BLOCK=512 + __launch_bounds__(512,2) = the only incantation that
//    yields the 128-VGPR budget (knob ledger r3-r6). Persistent state:
//    wp 64 + Cc 8 + pr 4 = 76 regs (r7/r11-proven no-spill).
template <bool FIRST>
__global__ __launch_bounds__(BLOCK, 2)
void mega(
    const __half* __restrict__ wbuf,
    const float* __restrict__ cbuf,
    const float* blur,
    const float* din,
    float* __restrict__ dout)
{
    __shared__ float sd[2][RR];

    const int tid = threadIdx.x;
    // XCD-aware bijective swizzle (512 = 8*64): neighbor tiles share halo
    // reads within one XCD's private L2.
    int bx = ((int)blockIdx.x % NXCD) * CHUNK + (int)blockIdx.x / NXCD;
    const int tj = bx % TJ_T; bx /= TJ_T;
    const int ti = bx % TI_T;
    const int b  = bx / TI_T;
    const int oi = ti * TILE_I - S_STEPS;  // region origin (image coords)
    const int oj = tj * TILE_J - S_STEPS;

    const float* dinb = (FIRST ? blur : din) + (size_t)b * HW;

    // --- stage d0 over the whole region (image-clamped; 7x512 exact) ---
#pragma unroll
    for (int q = 0; q < PPQ; q++) {
        int p = tid + q * BLOCK;
        int ri = p / RJ, rj = p - ri * RJ;
        int gi = iclamp(oi + ri, 0, Hh - 1);
        int gj = iclamp(oj + rj, 0, Ww - 1);
        sd[0][p] = dinb[gi * Ww + gj];
    }

    // --- load precomputed weights (fp16->fp32 once) + C per PAIR.
    // wp[q][k] = (w_k[px0], w_k[px1]); Cc[q] = (C0, C1);
    // pr[q] = region offset of px0 (low 16) | max(ring0,ring1) << 16 ---
    float2 wp[PPR][8];
    float2 Cc[PPR];
    int    pr[PPR];
#pragma unroll
    for (int q = 0; q < PPR; q++) {
        int pi = tid + q * BLOCK;
        if (pi < NPAIR) {
            int r0 = pi / NPAIR_ROW;
            int c0 = pi - r0 * NPAIR_ROW;
            int ri = 1 + r0;
            int rj = 1 + 2 * c0;           // odd -> aligned b64 tap bases
            int p  = ri * RJ + rj;
            int rngr = min(ri, RI - 1 - ri);
            int rng0 = min(rngr, min(rj,     RJ - 1 - rj));
            int rng1 = min(rngr, min(rj + 1, RJ - 2 - rj));
            pr[q] = p | (max(rng0, rng1) << 16);
            float Cv[2], wv[2][8];
#pragma unroll
            for (int x = 0; x < 2; x++) {
                int gi = iclamp(oi + ri, 0, Hh - 1);
                int gj = iclamp(oj + rj + x, 0, Ww - 1);
                int idx = b * HW + gi * Ww + gj;
                float4 w4 = *(const float4*)(wbuf + (size_t)idx * 8);
                const __half2* wh = (const __half2*)&w4;
                float2 w01 = __half22float2(wh[0]);
                float2 w23 = __half22float2(wh[1]);
                float2 w45 = __half22float2(wh[2]);
                float2 w67 = __half22float2(wh[3]);
                wv[x][0] = w01.x; wv[x][1] = w01.y;
                wv[x][2] = w23.x; wv[x][3] = w23.y;
                wv[x][4] = w45.x; wv[x][5] = w45.y;
                wv[x][6] = w67.x; wv[x][7] = w67.y;
                Cv[x] = cbuf[idx];
            }
            Cc[q] = make_float2(Cv[0], Cv[1]);
#pragma unroll
            for (int k = 0; k < 8; k++)
                wp[q][k] = make_float2(wv[0][k], wv[1][k]);
        } else {
            pr[q] = 0;                      // ring 0 -> never active
            Cc[q] = make_float2(0.0f, 0.0f);
#pragma unroll
            for (int k = 0; k < 8; k++) wp[q][k] = make_float2(0.0f, 0.0f);
        }
    }
    __syncthreads();

    // --- steps 1..7 in LDS; step s touches only pairs with maxring >= s ---
    int cur = 0;
#pragma unroll 1
    for (int s = 1; s < S_STEPS; ++s) {
        const float* s0 = sd[cur];
        float* s1 = sd[cur ^ 1];
#pragma unroll
        for (int q = 0; q < PPR; q++) {
            if ((pr[q] >> 16) >= s) {
                int p = pr[q] & 0xffff;
                // 12 distinct taps as 6 aligned b64 loads
                float2 uA = *(const float2*)(s0 + p - RJ - 1);   // (i-1: j-1, j)
                float2 uB = *(const float2*)(s0 + p - RJ + 1);   // (i-1: j+1, j+2)
                float2 mA = *(const float2*)(s0 + p - 1);        // (i  : j-1, j)
                float2 mB = *(const float2*)(s0 + p + 1);        // (i  : j+1, j+2)
                float2 dA = *(const float2*)(s0 + p + RJ - 1);   // (i+1: j-1, j)
                float2 dB = *(const float2*)(s0 + p + RJ + 1);   // (i+1: j+1, j+2)
                float ax = Cc[q].x, ay = Cc[q].y;
                ax = fmaf(wp[q][0].x, dB.x, ax);  ay = fmaf(wp[q][0].y, dB.y, ay);
                ax = fmaf(wp[q][1].x, dA.y, ax);  ay = fmaf(wp[q][1].y, dB.x, ay);
                ax = fmaf(wp[q][2].x, dA.x, ax);  ay = fmaf(wp[q][2].y, dA.y, ay);
                ax = fmaf(wp[q][3].x, mB.x, ax);  ay = fmaf(wp[q][3].y, mB.y, ay);
                ax = fmaf(wp[q][4].x, mA.x, ax);  ay = fmaf(wp[q][4].y, mA.y, ay);
                ax = fmaf(wp[q][5].x, uB.x, ax);  ay = fmaf(wp[q][5].y, uB.y, ay);
                ax = fmaf(wp[q][6].x, uA.y, ax);  ay = fmaf(wp[q][6].y, uB.x, ay);
                ax = fmaf(wp[q][7].x, uA.x, ax);  ay = fmaf(wp[q][7].y, uA.y, ay);
                s1[p]     = ax;
                s1[p + 1] = ay;
            }
        }
        __syncthreads();
        cur ^= 1;
    }

    // --- step 8: per-px center checks, write straight to global ---
    const float* s0 = sd[cur];
#pragma unroll
    for (int q = 0; q < PPR; q++) {
        if ((pr[q] >> 16) >= S_STEPS) {
            int p = pr[q] & 0xffff;
            float2 uA = *(const float2*)(s0 + p - RJ - 1);
            float2 uB = *(const float2*)(s0 + p - RJ + 1);
            float2 mA = *(const float2*)(s0 + p - 1);
            float2 mB = *(const float2*)(s0 + p + 1);
            float2 dA = *(const float2*)(s0 + p + RJ - 1);
            float2 dB = *(const float2*)(s0 + p + RJ + 1);
            float ax = Cc[q].x, ay = Cc[q].y;
            ax = fmaf(wp[q][0].x, dB.x, ax);  ay = fmaf(wp[q][0].y, dB.y, ay);
            ax = fmaf(wp[q][1].x, dA.y, ax);  ay = fmaf(wp[q][1].y, dB.x, ay);
            ax = fmaf(wp[q][2].x, dA.x, ax);  ay = fmaf(wp[q][2].y, dA.y, ay);
            ax = fmaf(wp[q][3].x, mB.x, ax);  ay = fmaf(wp[q][3].y, mB.y, ay);
            ax = fmaf(wp[q][4].x, mA.x, ax);  ay = fmaf(wp[q][4].y, mA.y, ay);
            ax = fmaf(wp[q][5].x, uB.x, ax);  ay = fmaf(wp[q][5].y, uB.y, ay);
            ax = fmaf(wp[q][6].x, uA.y, ax);  ay = fmaf(wp[q][6].y, uB.x, ay);
            ax = fmaf(wp[q][7].x, uA.x, ax);  ay = fmaf(wp[q][7].y, uA.y, ay);
            int ri = p / RJ, rj = p - ri * RJ;
            // maxring >= 8 guarantees ri in [8, RI-8); cols checked per px.
            int gbase = b * HW + (oi + ri) * Ww + (oj + rj);
            if (rj >= S_STEPS && rj < RJ - S_STEPS)
                dout[gbase]     = ax;
            if (rj + 1 >= S_STEPS && rj + 1 < RJ - S_STEPS)
                dout[gbase + 1] = ay;
        }
    }
}

extern "C" void kernel_launch(void* const* d_in, const int* in_sizes, int n_in,
                              void* d_out, int out_size, void* d_ws, size_t ws_size,
                              hipStream_t stream) {
    const float* guidance = (const float*)d_in[0];
    const float* blur     = (const float*)d_in[1];
    const float* sparse   = (const float*)d_in[2];
    float* out = (float*)d_out;

    char* ws = (char*)d_ws;
    float* bufA = (float*)ws;
    float* bufB = bufA + NPIX;
    __half* wbuf = (__half*)(bufB + NPIX);          // NPIX*8 fp16 = 15.7 MB
    float*  cbuf = (float*)(wbuf + (size_t)NPIX * 8);

    const int threads = 256;
    const int blocks = (NPIX + threads - 1) / threads;
    affinity_norm<<<blocks, threads, 0, stream>>>(guidance, blur, sparse, wbuf, cbuf);

    // 24 steps = 3 launches x 8 fused steps
    mega<true ><<<GRID, BLOCK, 0, stream>>>(wbuf, cbuf, blur, nullptr, bufA);
    mega<false><<<GRID, BLOCK, 0, stream>>>(wbuf, cbuf, nullptr, bufA, bufB);
    mega<false><<<GRID, BLOCK, 0, stream>>>(wbuf, cbuf, nullptr, bufB, out);
}